// Round 4
// baseline (675.116 us; speedup 1.0000x reference)
//
#include <hip/hip_runtime.h>
#include <math.h>

// Problem constants (match reference)
#define NB 128          // graphs in batch
#define NL 1024         // links per graph
static constexpr float P_TX    = 10.0f;
static constexpr float P_NOISE = 6.2946e-14f;
static constexpr float INV_LN2 = 1.44269504088896340736f;

// Tiling: 4 waves/block, 8 rows/wave -> 32 rows/block, 32 blocks/graph.
#define RPW 8                       // rows per wave
#define NWAVES 4
#define RPB (RPW * NWAVES)          // 32 rows per block
#define BLKS_PER_GRAPH (NL / RPB)   // 32

// Native clang vector type for __builtin_nontemporal_load
// (HIP's float4 is a class type the builtin rejects).
typedef float fvec4 __attribute__((ext_vector_type(4)));

// ---------------------------------------------------------------------------
// Workspace layout: float partial[BLKS_PER_GRAPH][NB]
//   partial[c][b] = sum of R over the 32 rows of chunk c of graph b.
// Every slot is written unconditionally -> no init kernel, no atomics,
// safe against poisoned workspace.
// ---------------------------------------------------------------------------

__global__ __launch_bounds__(256) void rows_kernel(
        const float* __restrict__ prob,   // [NB*NL, 2]
        const float* __restrict__ H,      // [NB, NL, NL]
        float* __restrict__ partial)      // [BLKS_PER_GRAPH][NB]
{
    __shared__ float py[NL];        // P_TX * y for this graph
    __shared__ float rpart[NWAVES]; // per-wave partial sum of R

    const int b    = blockIdx.x / BLKS_PER_GRAPH;
    const int c    = blockIdx.x % BLKS_PER_GRAPH;
    const int row0 = c * RPB;
    const int tid  = threadIdx.x;

    // Stage Py[b][:] into LDS (coalesced float2 loads of prob pairs).
    {
        const float2* p2 = (const float2*)prob + (size_t)b * NL;
        #pragma unroll
        for (int i = 0; i < NL / 256; ++i) {
            int j = tid + 256 * i;
            py[j] = P_TX * p2[j].y;
        }
    }
    __syncthreads();

    const int wave  = tid >> 6;
    const int lane  = tid & 63;
    const int kbase = row0 + wave * RPW;
    const float* __restrict__ Hbase = H + ((size_t)b * NL + kbase) * NL;

    // The 8 rows of this wave have k = kbase..kbase+7; kbase % 8 == 0, so
    // all 8 diagonals live in the same 256-col iteration it_d (wave-uniform).
    const int it_d = kbase >> 8;

    float acc[RPW];
    float hdsave[RPW];   // diagonal H[k][k], valid in the owning lane only
    #pragma unroll
    for (int r = 0; r < RPW; ++r) { acc[r] = 0.0f; hdsave[r] = 0.0f; }

    // total[b,k] = sum_j H[b,k,j]^2 * Py[j]
    // One LDS float4 read shared across 8 rows; 8 nontemporal 16B global
    // loads in flight per lane (H is streamed exactly once -> bypass L2/L3).
    // Diagonal elements are captured in-loop (NT stream never hits L2, so a
    // post-loop re-read would be a cold HBM miss).
    #pragma unroll
    for (int it = 0; it < 4; ++it) {
        const int j = it * 256 + lane * 4;
        const float4 p4 = *(const float4*)(&py[j]);
        #pragma unroll
        for (int r = 0; r < RPW; ++r) {
            fvec4 h4 = __builtin_nontemporal_load(
                            (const fvec4*)(Hbase + (size_t)r * NL + j));
            if (it == it_d) {                       // wave-uniform scalar branch
                const int k = kbase + r;
                if (lane == ((k >> 2) & 63)) {      // owning lane
                    const int cmp = k & 3;
                    hdsave[r] = (cmp == 0) ? h4.x :
                                (cmp == 1) ? h4.y :
                                (cmp == 2) ? h4.z : h4.w;
                }
            }
            acc[r] = fmaf(h4.x * h4.x, p4.x, acc[r]);
            acc[r] = fmaf(h4.y * h4.y, p4.y, acc[r]);
            acc[r] = fmaf(h4.z * h4.z, p4.z, acc[r]);
            acc[r] = fmaf(h4.w * h4.w, p4.w, acc[r]);
        }
    }

    // 64-lane wave reductions (result valid on lane 0).
    #pragma unroll
    for (int r = 0; r < RPW; ++r) {
        float a = acc[r];
        #pragma unroll
        for (int off = 32; off >= 1; off >>= 1)
            a += __shfl_down(a, off, 64);
        acc[r] = a;
    }

    // Broadcast each row's diagonal to all lanes; lane 0 computes R.
    float s = 0.0f;
    #pragma unroll
    for (int r = 0; r < RPW; ++r) {
        const int k  = kbase + r;
        float hd     = __shfl(hdsave[r], (k >> 2) & 63, 64);
        if (lane == 0) {
            float sig    = hd * hd * py[k];
            float interf = acc[r] - sig + P_NOISE;
            s += log1pf(sig / interf) * INV_LN2;
        }
    }
    if (lane == 0) rpart[wave] = s;
    __syncthreads();

    if (tid == 0) {
        // partial[c][b]: coalesced across b for the final reduction.
        partial[(size_t)c * NB + b] =
            rpart[0] + rpart[1] + rpart[2] + rpart[3];
    }
}

// loss = mean_b 1 / sum_c partial[c][b]; single block of 128 threads.
__global__ void final_kernel(const float* __restrict__ partial,
                             float* __restrict__ out)
{
    int b = threadIdx.x;             // 0..127 = graph index
    float rsum = 0.0f;
    #pragma unroll
    for (int c = 0; c < BLKS_PER_GRAPH; ++c)
        rsum += partial[(size_t)c * NB + b];   // coalesced across lanes

    float v = (1.0f / rsum) * (1.0f / (float)NB);
    #pragma unroll
    for (int off = 32; off >= 1; off >>= 1)
        v += __shfl_down(v, off, 64);
    __shared__ float ps[2];
    if ((b & 63) == 0) ps[b >> 6] = v;
    __syncthreads();
    if (b == 0) out[0] = ps[0] + ps[1];
}

extern "C" void kernel_launch(void* const* d_in, const int* in_sizes, int n_in,
                              void* d_out, int out_size, void* d_ws, size_t ws_size,
                              hipStream_t stream) {
    const float* prob    = (const float*)d_in[0];  // [NB*NL, 2]
    const float* H       = (const float*)d_in[1];  // [NB, NL, NL]
    float* out     = (float*)d_out;                // scalar
    float* partial = (float*)d_ws;                 // BLKS_PER_GRAPH*NB floats

    rows_kernel<<<NB * BLKS_PER_GRAPH, 256, 0, stream>>>(prob, H, partial);
    final_kernel<<<1, 128, 0, stream>>>(partial, out);
}

// Round 5
// 668.677 us; speedup vs baseline: 1.0096x; 1.0096x over previous
//
#include <hip/hip_runtime.h>
#include <math.h>

// Problem constants (match reference)
#define NB 128          // graphs in batch
#define NL 1024         // links per graph
static constexpr float P_TX    = 10.0f;
static constexpr float P_NOISE = 6.2946e-14f;
static constexpr float INV_LN2 = 1.44269504088896340736f;

// Tiling: 4 waves/block, 8 rows/wave -> 32 rows/block, 32 blocks/graph.
#define RPW 8                       // rows per wave
#define NWAVES 4
#define RPB (RPW * NWAVES)          // 32 rows per block
#define BLKS_PER_GRAPH (NL / RPB)   // 32

// Native clang vector type for __builtin_nontemporal_load
// (HIP's float4 is a class type the builtin rejects).
typedef float fvec4 __attribute__((ext_vector_type(4)));

// ---------------------------------------------------------------------------
// Workspace layout: float partial[BLKS_PER_GRAPH][NB]
//   partial[c][b] = sum of R over the 32 rows of chunk c of graph b.
// Every slot is written unconditionally -> no init kernel, no atomics,
// safe against poisoned workspace.
// ---------------------------------------------------------------------------

__global__ __launch_bounds__(256) void rows_kernel(
        const float* __restrict__ prob,   // [NB*NL, 2]
        const float* __restrict__ H,      // [NB, NL, NL]
        float* __restrict__ partial)      // [BLKS_PER_GRAPH][NB]
{
    __shared__ float py[NL];        // P_TX * y for this graph
    __shared__ float rpart[NWAVES]; // per-wave partial sum of R

    const int b    = blockIdx.x / BLKS_PER_GRAPH;
    const int c    = blockIdx.x % BLKS_PER_GRAPH;
    const int row0 = c * RPB;
    const int tid  = threadIdx.x;

    // Stage Py[b][:] into LDS (coalesced float2 loads of prob pairs).
    {
        const float2* p2 = (const float2*)prob + (size_t)b * NL;
        #pragma unroll
        for (int i = 0; i < NL / 256; ++i) {
            int j = tid + 256 * i;
            py[j] = P_TX * p2[j].y;
        }
    }
    __syncthreads();

    const int wave  = tid >> 6;
    const int lane  = tid & 63;
    const int kbase = row0 + wave * RPW;
    const float* __restrict__ Hbase = H + ((size_t)b * NL + kbase) * NL;

    float acc[RPW];
    #pragma unroll
    for (int r = 0; r < RPW; ++r) acc[r] = 0.0f;

    // total[b,k] = sum_j H[b,k,j]^2 * Py[j]
    // One LDS float4 read shared across 8 rows; 8 nontemporal 16B global
    // loads in flight per lane (H is streamed exactly once; nt = evict-first
    // hint keeps the stream from thrashing L2/L3).
    #pragma unroll
    for (int it = 0; it < 4; ++it) {
        const int j = it * 256 + lane * 4;
        const float4 p4 = *(const float4*)(&py[j]);
        #pragma unroll
        for (int r = 0; r < RPW; ++r) {
            fvec4 h4 = __builtin_nontemporal_load(
                            (const fvec4*)(Hbase + (size_t)r * NL + j));
            acc[r] = fmaf(h4.x * h4.x, p4.x, acc[r]);
            acc[r] = fmaf(h4.y * h4.y, p4.y, acc[r]);
            acc[r] = fmaf(h4.z * h4.z, p4.z, acc[r]);
            acc[r] = fmaf(h4.w * h4.w, p4.w, acc[r]);
        }
    }

    // 64-lane wave reductions (result valid on lane 0).
    #pragma unroll
    for (int r = 0; r < RPW; ++r) {
        float a = acc[r];
        #pragma unroll
        for (int off = 32; off >= 1; off >>= 1)
            a += __shfl_down(a, off, 64);
        acc[r] = a;
    }

    if (lane == 0) {
        float s = 0.0f;
        #pragma unroll
        for (int r = 0; r < RPW; ++r) {
            const int k  = kbase + r;
            float hd     = Hbase[(size_t)r * NL + k];   // diagonal, L2-hot
            float sig    = hd * hd * py[k];
            float interf = acc[r] - sig + P_NOISE;
            s += log1pf(sig / interf) * INV_LN2;
        }
        rpart[wave] = s;
    }
    __syncthreads();

    if (tid == 0) {
        // partial[c][b]: coalesced across b for the final reduction.
        partial[(size_t)c * NB + b] =
            rpart[0] + rpart[1] + rpart[2] + rpart[3];
    }
}

// loss = mean_b 1 / sum_c partial[c][b]; single block of 128 threads.
__global__ void final_kernel(const float* __restrict__ partial,
                             float* __restrict__ out)
{
    int b = threadIdx.x;             // 0..127 = graph index
    float rsum = 0.0f;
    #pragma unroll
    for (int c = 0; c < BLKS_PER_GRAPH; ++c)
        rsum += partial[(size_t)c * NB + b];   // coalesced across lanes

    float v = (1.0f / rsum) * (1.0f / (float)NB);
    #pragma unroll
    for (int off = 32; off >= 1; off >>= 1)
        v += __shfl_down(v, off, 64);
    __shared__ float ps[2];
    if ((b & 63) == 0) ps[b >> 6] = v;
    __syncthreads();
    if (b == 0) out[0] = ps[0] + ps[1];
}

extern "C" void kernel_launch(void* const* d_in, const int* in_sizes, int n_in,
                              void* d_out, int out_size, void* d_ws, size_t ws_size,
                              hipStream_t stream) {
    const float* prob    = (const float*)d_in[0];  // [NB*NL, 2]
    const float* H       = (const float*)d_in[1];  // [NB, NL, NL]
    float* out     = (float*)d_out;                // scalar
    float* partial = (float*)d_ws;                 // BLKS_PER_GRAPH*NB floats

    rows_kernel<<<NB * BLKS_PER_GRAPH, 256, 0, stream>>>(prob, H, partial);
    final_kernel<<<1, 128, 0, stream>>>(partial, out);
}